// Round 6
// baseline (388.850 us; speedup 1.0000x reference)
//
#include <hip/hip_runtime.h>
#include <hip/hip_bf16.h>

typedef __bf16 bf16_t;
typedef __bf16 bf16x4 __attribute__((ext_vector_type(4)));
typedef __bf16 bf16x8 __attribute__((ext_vector_type(8)));
typedef float f32x4 __attribute__((ext_vector_type(4)));

#define IN_DIM 21
#define HID 512
#define OUT_DIM 21
#define M_TILE 32
#define THREADS 256   // 4 waves/block; LDS ~35 KB -> 4 blocks/CU. Each SIMD hosts 4 waves
                      // from 4 DIFFERENT blocks -> independent phase offsets cover stalls.

// XOR swizzle in element units: flips col bits 3..5 with row low bits.
// For all h accesses row&7 == l16&7, so the XOR term is a per-lane constant.
__device__ __forceinline__ int swz(int row, int col) {
    return col ^ ((row & 7) << 3);
}

// ---- prep: convert weights fp32 -> bf16 *fragment-major* layouts in ws ----
// Fragment for 16x16x32 mfma: element (outer = tile*16 + (lane&15),
// k = k0 + (lane>>4)*8 + j) stored at frag_base + lane*8 + j.
// W2f: [kstep(16)][ntile(32)][512]   W1f: [ntile(32)][512] (k>=21 zero)
// W3f: [kstep(16)][otile(2)][512]    (o>=21 zero)
__global__ void prep_kernel(const float* __restrict__ W1, const float* __restrict__ W2,
                            const float* __restrict__ W3,
                            bf16_t* __restrict__ W1f, bf16_t* __restrict__ W2f,
                            bf16_t* __restrict__ W3f, float* __restrict__ accum) {
    if (blockIdx.x == 0 && threadIdx.x == 0) {
        accum[0] = 0.0f; accum[1] = 0.0f;
        ((unsigned*)accum)[2] = 0u;   // last-block ticket
    }
    int i = blockIdx.x * blockDim.x + threadIdx.x;
    int stride = gridDim.x * blockDim.x;
    const int NW2 = HID * HID;     // 262144
    const int NW1 = 32 * 512;      // 16384
    const int NW3 = 16 * 2 * 512;  // 16384
    for (; i < NW2 + NW1 + NW3; i += stride) {
        if (i < NW2) {
            int j = i & 7, lane = (i >> 3) & 63, ntile = (i >> 9) & 31, kstep = i >> 14;
            int n = ntile * 16 + (lane & 15);
            int k = kstep * 32 + (lane >> 4) * 8 + j;
            W2f[i] = (bf16_t)W2[n * HID + k];
        } else if (i < NW2 + NW1) {
            int t = i - NW2;
            int j = t & 7, lane = (t >> 3) & 63, ntile = t >> 9;
            int n = ntile * 16 + (lane & 15);
            int k = (lane >> 4) * 8 + j;
            W1f[t] = (k < IN_DIM) ? (bf16_t)W1[n * IN_DIM + k] : (bf16_t)0.0f;
        } else {
            int t = i - NW2 - NW1;
            int j = t & 7, lane = (t >> 3) & 63, ot = (t >> 9) & 1, kstep = t >> 10;
            int o = ot * 16 + (lane & 15);
            int k = kstep * 32 + (lane >> 4) * 8 + j;
            W3f[t] = (o < OUT_DIM) ? (bf16_t)W3[o * HID + k] : (bf16_t)0.0f;
        }
    }
}

// ---- fused MLP + loss ----
// Operand-swapped mfma: D = A(W-frag) * B(act-frag) -> D col = lane&15 = row m,
// D row = quad*4+r = feature n. Bias pre-loaded into the accumulator (C-in).
// K-loop ROLLED, NO manual prefetch buffers and NO in-flight source-reg reuse
// (round 5 lesson: WAR on MFMA sources serializes). Latency cover = 4
// independent blocks per CU.
__global__ __launch_bounds__(THREADS, 4)  // 4 waves/EU -> reg cap 128/wave
void fused_kernel(const float* __restrict__ V, const float* __restrict__ gt,
                  const float* __restrict__ b1, const float* __restrict__ b2,
                  const float* __restrict__ b3,
                  const bf16_t* __restrict__ W1f, const bf16_t* __restrict__ W2f,
                  const bf16_t* __restrict__ W3f, float* __restrict__ accum,
                  float* __restrict__ out) {
    __shared__ __align__(16) bf16_t vlds[M_TILE][40];  // stride 80 B: 2-way max on b128 reads
    __shared__ __align__(16) bf16_t h[M_TILE][HID];    // single buffer: h1, then h2 in-place
    __shared__ float redbuf[8];

    const int tid  = threadIdx.x;
    const int wave = tid >> 6;       // 0..3
    const int lane = tid & 63;
    const int quad = lane >> 4;
    const int l16  = lane & 15;
    const int sx   = (l16 & 7) << 3; // per-lane swizzle XOR constant
    const long row0 = (long)blockIdx.x * M_TILE;

    // phase 0: velocities tile -> LDS bf16, k padded to 32 with zeros
    for (int idx = tid; idx < M_TILE * 32; idx += THREADS) {
        int r = idx >> 5, c = idx & 31;
        float v = (c < IN_DIM) ? V[(row0 + r) * IN_DIM + c] : 0.0f;
        vlds[r][c] = (bf16_t)v;
    }
    __syncthreads();

    // phase 1: h1[m][n] = relu(V @ W1^T + b1); wave covers n in [wave*128, wave*128+128)
    {
        bf16x8 bv[2];
        #pragma unroll
        for (int mt = 0; mt < 2; ++mt)
            bv[mt] = *reinterpret_cast<const bf16x8*>(&vlds[mt * 16 + l16][quad * 8]);
        #pragma unroll
        for (int nt = 0; nt < 8; ++nt) {
            int ntile = wave * 8 + nt;
            bf16x8 w1 = *reinterpret_cast<const bf16x8*>(W1f + ntile * 512 + lane * 8);
            f32x4 bias = *reinterpret_cast<const f32x4*>(b1 + ntile * 16 + quad * 4);
            int n0 = ntile * 16 + quad * 4;
            #pragma unroll
            for (int mt = 0; mt < 2; ++mt) {
                f32x4 c = bias;   // bias via C-in
                c = __builtin_amdgcn_mfma_f32_16x16x32_bf16(w1, bv[mt], c, 0, 0, 0);
                bf16x4 pk;
                #pragma unroll
                for (int r = 0; r < 4; ++r)
                    pk[r] = (bf16_t)(c[r] > 0.0f ? c[r] : 0.0f);
                int m = mt * 16 + l16;
                *reinterpret_cast<bf16x4*>(&h[m][n0 ^ sx]) = pk;
            }
        }
    }
    __syncthreads();

    // phase 2: h2 = relu(h1 @ W2^T + b2). Per wave: M=32, N=128, K=512.
    // Live regs: 64 acc + 32 aw + 8 bh + addr ~ 110 <= 128. Rolled loop:
    // issue 8 aw (global) + 2 bh (ds) per K-step, then 16 MFMAs; the L2/ds
    // waits of this block are covered by the other 3 resident blocks.
    {
        f32x4 acc[2][8];
        #pragma unroll
        for (int nt = 0; nt < 8; ++nt) {
            f32x4 bias = *reinterpret_cast<const f32x4*>(b2 + (wave * 8 + nt) * 16 + quad * 4);
            acc[0][nt] = bias;
            acc[1][nt] = bias;
        }

        const bf16_t* w2p = W2f + wave * 8 * 512 + lane * 8;  // + nt*512 + ks*16384

        #pragma unroll 1
        for (int ks = 0; ks < 16; ++ks) {
            bf16x8 aw[8];
            #pragma unroll
            for (int nt = 0; nt < 8; ++nt)
                aw[nt] = *reinterpret_cast<const bf16x8*>(w2p + ks * 16384 + nt * 512);
            bf16x8 bh[2];
            #pragma unroll
            for (int mt = 0; mt < 2; ++mt)
                bh[mt] = *reinterpret_cast<const bf16x8*>(
                    &h[mt * 16 + l16][(ks * 32 + quad * 8) ^ sx]);
            #pragma unroll
            for (int nt = 0; nt < 8; ++nt)
                #pragma unroll
                for (int mt = 0; mt < 2; ++mt)
                    acc[mt][nt] = __builtin_amdgcn_mfma_f32_16x16x32_bf16(aw[nt], bh[mt], acc[mt][nt], 0, 0, 0);
        }
        __syncthreads();  // all reads of h1 complete before overwrite

        #pragma unroll
        for (int nt = 0; nt < 8; ++nt) {
            int n0 = (wave * 8 + nt) * 16 + quad * 4;
            #pragma unroll
            for (int mt = 0; mt < 2; ++mt) {
                bf16x4 pk;
                #pragma unroll
                for (int r = 0; r < 4; ++r)
                    pk[r] = (bf16_t)(acc[mt][nt][r] > 0.0f ? acc[mt][nt][r] : 0.0f);
                int m = mt * 16 + l16;
                *reinterpret_cast<bf16x4*>(&h[m][n0 ^ sx]) = pk;
            }
        }
    }
    __syncthreads();

    // phase 3: out = h2 @ W3^T + b3, then loss. 4 jobs = 2 mt x 2 ot = 4 waves.
    {
        const int mt = wave >> 1;
        const int ot = wave & 1;
        const int o0 = ot * 16 + quad * 4;
        const long grow = row0 + mt * 16 + l16;

        // hoist gt/b3 loads above the K-loop (hide latency under MFMAs)
        float g[4], b3v[4];
        #pragma unroll
        for (int r = 0; r < 4; ++r) {
            bool v = (o0 + r) < OUT_DIM;
            g[r]   = v ? gt[grow * OUT_DIM + o0 + r] : -10000.0f;
            b3v[r] = v ? b3[o0 + r] : 0.0f;
        }

        f32x4 acc3a = {b3v[0], b3v[1], b3v[2], b3v[3]};  // bias via C-in
        f32x4 acc3b = {0.0f, 0.0f, 0.0f, 0.0f};
        const int rr = mt * 16 + l16;
        #pragma unroll
        for (int ks = 0; ks < 16; ks += 2) {
            bf16x8 bh0 = *reinterpret_cast<const bf16x8*>(&h[rr][(ks * 32 + quad * 8) ^ sx]);
            bf16x8 bh1 = *reinterpret_cast<const bf16x8*>(&h[rr][((ks + 1) * 32 + quad * 8) ^ sx]);
            bf16x8 aw0 = *reinterpret_cast<const bf16x8*>(W3f + (ks * 2 + ot) * 512 + lane * 8);
            bf16x8 aw1 = *reinterpret_cast<const bf16x8*>(W3f + ((ks + 1) * 2 + ot) * 512 + lane * 8);
            acc3a = __builtin_amdgcn_mfma_f32_16x16x32_bf16(aw0, bh0, acc3a, 0, 0, 0);
            acc3b = __builtin_amdgcn_mfma_f32_16x16x32_bf16(aw1, bh1, acc3b, 0, 0, 0);
        }

        float num = 0.0f, den = 0.0f;
        #pragma unroll
        for (int r = 0; r < 4; ++r) {
            if ((o0 + r) < OUT_DIM) {
                float pred = acc3a[r] + acc3b[r];
                if (g[r] > -5000.0f) {
                    float w = (floorf(pred * 2.0f) == floorf(g[r] * 2.0f)) ? 0.5f : 1.0f;
                    num += fabsf(pred * w - g[r] * w);
                    den += 1.0f;
                }
            }
        }
        #pragma unroll
        for (int off = 32; off > 0; off >>= 1) {
            num += __shfl_down(num, off);
            den += __shfl_down(den, off);
        }
        if (lane == 0) { redbuf[wave * 2] = num; redbuf[wave * 2 + 1] = den; }
    }
    __syncthreads();
    if (tid == 0) {
        float nB = redbuf[0] + redbuf[2] + redbuf[4] + redbuf[6];
        float dB = redbuf[1] + redbuf[3] + redbuf[5] + redbuf[7];
        atomicAdd(accum, nB);
        atomicAdd(accum + 1, dB);
        __threadfence();
        unsigned prev = atomicAdd((unsigned*)(accum + 2), 1u);
        if (prev == gridDim.x - 1) {   // last block finalizes (no extra launch)
            __threadfence();
            float num = __hip_atomic_load(accum,     __ATOMIC_RELAXED, __HIP_MEMORY_SCOPE_AGENT);
            float den = __hip_atomic_load(accum + 1, __ATOMIC_RELAXED, __HIP_MEMORY_SCOPE_AGENT);
            out[0] = num / den;
        }
    }
}

extern "C" void kernel_launch(void* const* d_in, const int* in_sizes, int n_in,
                              void* d_out, int out_size, void* d_ws, size_t ws_size,
                              hipStream_t stream) {
    const float* V  = (const float*)d_in[0];
    const float* gt = (const float*)d_in[1];
    const float* W1 = (const float*)d_in[2];
    const float* b1 = (const float*)d_in[3];
    const float* W2 = (const float*)d_in[4];
    const float* b2 = (const float*)d_in[5];
    const float* W3 = (const float*)d_in[6];
    const float* b3 = (const float*)d_in[7];
    float* out = (float*)d_out;

    char* ws = (char*)d_ws;
    float* accum = (float*)ws;                                       // 2 floats + 1 ticket
    bf16_t* W2f = (bf16_t*)(ws + 16);                                // 512 KB
    bf16_t* W1f = (bf16_t*)(ws + 16 + 512 * 512 * 2);                // 32 KB
    bf16_t* W3f = (bf16_t*)(ws + 16 + 512 * 512 * 2 + 32 * 512 * 2); // 32 KB

    int Brows = in_sizes[0] / IN_DIM;   // 131072
    int grid = Brows / M_TILE;          // 4096

    prep_kernel<<<576, 512, 0, stream>>>(W1, W2, W3, W1f, W2f, W3f, accum);
    fused_kernel<<<grid, THREADS, 0, stream>>>(V, gt, b1, b2, b3, W1f, W2f, W3f, accum, out);
}

// Round 7
// 221.189 us; speedup vs baseline: 1.7580x; 1.7580x over previous
//
#include <hip/hip_runtime.h>
#include <hip/hip_bf16.h>

typedef __bf16 bf16_t;
typedef __bf16 bf16x4 __attribute__((ext_vector_type(4)));
typedef __bf16 bf16x8 __attribute__((ext_vector_type(8)));
typedef float f32x4 __attribute__((ext_vector_type(4)));

#define IN_DIM 21
#define HID 512
#define OUT_DIM 21
#define M_TILE 64
#define THREADS 1024  // 16 waves, per-wave 64x32 tile: acc=32 regs -> headroom for the
                      // fully-unrolled, multi-buffered phase-2 pipeline (round-1 structure,
                      // the best measured config; R2 proved acc=64 + full unroll spills).

// XOR swizzle in element units: flips col bits 3..5 with row low bits.
// For all h accesses row&7 == l16&7, so the XOR term is a per-lane constant.
__device__ __forceinline__ int swz(int row, int col) {
    return col ^ ((row & 7) << 3);
}

// ---- prep: convert weights fp32 -> bf16 *fragment-major* layouts in ws ----
// Fragment for 16x16x32 mfma: element (outer = tile*16 + (lane&15),
// k = k0 + (lane>>4)*8 + j) stored at frag_base + lane*8 + j.
// W2f: [kstep(16)][ntile(32)][512]   W1f: [ntile(32)][512] (k>=21 zero)
// W3f: [kstep(16)][otile(2)][512]    (o>=21 zero)
__global__ void prep_kernel(const float* __restrict__ W1, const float* __restrict__ W2,
                            const float* __restrict__ W3,
                            bf16_t* __restrict__ W1f, bf16_t* __restrict__ W2f,
                            bf16_t* __restrict__ W3f, float* __restrict__ accum) {
    if (blockIdx.x == 0 && threadIdx.x == 0) {
        accum[0] = 0.0f; accum[1] = 0.0f;
        ((unsigned*)accum)[2] = 0u;   // last-block ticket
    }
    int i = blockIdx.x * blockDim.x + threadIdx.x;
    int stride = gridDim.x * blockDim.x;
    const int NW2 = HID * HID;     // 262144
    const int NW1 = 32 * 512;      // 16384
    const int NW3 = 16 * 2 * 512;  // 16384
    for (; i < NW2 + NW1 + NW3; i += stride) {
        if (i < NW2) {
            int j = i & 7, lane = (i >> 3) & 63, ntile = (i >> 9) & 31, kstep = i >> 14;
            int n = ntile * 16 + (lane & 15);
            int k = kstep * 32 + (lane >> 4) * 8 + j;
            W2f[i] = (bf16_t)W2[n * HID + k];
        } else if (i < NW2 + NW1) {
            int t = i - NW2;
            int j = t & 7, lane = (t >> 3) & 63, ntile = t >> 9;
            int n = ntile * 16 + (lane & 15);
            int k = (lane >> 4) * 8 + j;
            W1f[t] = (k < IN_DIM) ? (bf16_t)W1[n * IN_DIM + k] : (bf16_t)0.0f;
        } else {
            int t = i - NW2 - NW1;
            int j = t & 7, lane = (t >> 3) & 63, ot = (t >> 9) & 1, kstep = t >> 10;
            int o = ot * 16 + (lane & 15);
            int k = kstep * 32 + (lane >> 4) * 8 + j;
            W3f[t] = (o < OUT_DIM) ? (bf16_t)W3[o * HID + k] : (bf16_t)0.0f;
        }
    }
}

// ---- fused MLP + loss ----
// Operand-swapped mfma: D = A(W-frag) * B(act-frag) -> D col = lane&15 = row m,
// D row = quad*4+r = feature n. Bias pre-loaded into the accumulator (C-in).
// Phase-2 pipeline: FULL unroll + explicit rotating buffers with SEPARATE names
// (depth-2 mod-3 for weights, depth-1 ping-pong for LDS activations). Never
// reuse an MFMA source reg in-flight (round-5 WAR lesson). acc kept at 32 regs
// so the live set (~112) stays under the 128 cap (round-2 spill lesson).
__global__ __launch_bounds__(THREADS, 4)  // 4 waves/EU -> reg cap 128/wave
void fused_kernel(const float* __restrict__ V, const float* __restrict__ gt,
                  const float* __restrict__ b1, const float* __restrict__ b2,
                  const float* __restrict__ b3,
                  const bf16_t* __restrict__ W1f, const bf16_t* __restrict__ W2f,
                  const bf16_t* __restrict__ W3f, float* __restrict__ accum,
                  float* __restrict__ out) {
    __shared__ __align__(16) bf16_t vlds[M_TILE][40];  // stride 80 B: 2-way max on b128 reads
    __shared__ __align__(16) bf16_t h[M_TILE][HID];    // single buffer: h1, then h2 in-place
    __shared__ float redbuf[16];

    const int tid  = threadIdx.x;
    const int wave = tid >> 6;       // 0..15
    const int lane = tid & 63;
    const int quad = lane >> 4;
    const int l16  = lane & 15;
    const int sx   = (l16 & 7) << 3; // per-lane swizzle XOR constant
    const long row0 = (long)blockIdx.x * M_TILE;

    // phase 0: velocities tile -> LDS bf16, k padded to 32 with zeros
    for (int idx = tid; idx < M_TILE * 32; idx += THREADS) {
        int r = idx >> 5, c = idx & 31;
        float v = (c < IN_DIM) ? V[(row0 + r) * IN_DIM + c] : 0.0f;
        vlds[r][c] = (bf16_t)v;
    }
    __syncthreads();

    // phase 1: h1[m][n] = relu(V @ W1^T + b1); wave covers n in [wave*32, wave*32+32)
    {
        bf16x8 bv[4];
        #pragma unroll
        for (int mt = 0; mt < 4; ++mt)
            bv[mt] = *reinterpret_cast<const bf16x8*>(&vlds[mt * 16 + l16][quad * 8]);
        #pragma unroll
        for (int nt = 0; nt < 2; ++nt) {
            int ntile = wave * 2 + nt;
            bf16x8 w1 = *reinterpret_cast<const bf16x8*>(W1f + ntile * 512 + lane * 8);
            f32x4 bias = *reinterpret_cast<const f32x4*>(b1 + ntile * 16 + quad * 4);
            int n0 = ntile * 16 + quad * 4;
            #pragma unroll
            for (int mt = 0; mt < 4; ++mt) {
                f32x4 c = bias;   // bias via C-in
                c = __builtin_amdgcn_mfma_f32_16x16x32_bf16(w1, bv[mt], c, 0, 0, 0);
                bf16x4 pk;
                #pragma unroll
                for (int r = 0; r < 4; ++r)
                    pk[r] = (bf16_t)(c[r] > 0.0f ? c[r] : 0.0f);
                int m = mt * 16 + l16;
                *reinterpret_cast<bf16x4*>(&h[m][n0 ^ sx]) = pk;
            }
        }
    }
    __syncthreads();

    // phase 2: h2 = relu(h1 @ W2^T + b2). Per wave: M=64, N=32, K=512.
    // Round-1 pipeline: depth-2 mod-3 rotation for the two W2f streams,
    // depth-1 ping-pong (ac/an) for the LDS activation fragments, full unroll.
    {
        f32x4 acc[4][2];
        #pragma unroll
        for (int nt = 0; nt < 2; ++nt) {
            f32x4 bias = *reinterpret_cast<const f32x4*>(b2 + (wave * 2 + nt) * 16 + quad * 4);
            #pragma unroll
            for (int mt = 0; mt < 4; ++mt)
                acc[mt][nt] = bias;   // bias via C-in
        }

        const bf16_t* w2p0 = W2f + (wave * 2 + 0) * 512 + lane * 8;
        const bf16_t* w2p1 = W2f + (wave * 2 + 1) * 512 + lane * 8;

        bf16x8 b0buf[3], b1buf[3];
        bf16x8 ac[4], an[4];
        #pragma unroll
        for (int p = 0; p < 2; ++p) {
            b0buf[p] = *reinterpret_cast<const bf16x8*>(w2p0 + p * 16384);
            b1buf[p] = *reinterpret_cast<const bf16x8*>(w2p1 + p * 16384);
        }
        #pragma unroll
        for (int mt = 0; mt < 4; ++mt)
            ac[mt] = *reinterpret_cast<const bf16x8*>(&h[mt * 16 + l16][(quad * 8) ^ sx]);

        #pragma unroll
        for (int ks = 0; ks < 16; ++ks) {
            if (ks + 2 < 16) {  // prefetch weights for ks+2 (depth 2, separate buffers)
                b0buf[(ks + 2) % 3] = *reinterpret_cast<const bf16x8*>(w2p0 + (ks + 2) * 16384);
                b1buf[(ks + 2) % 3] = *reinterpret_cast<const bf16x8*>(w2p1 + (ks + 2) * 16384);
            }
            if (ks + 1 < 16) {  // prefetch activations for ks+1 (depth 1)
                #pragma unroll
                for (int mt = 0; mt < 4; ++mt)
                    an[mt] = *reinterpret_cast<const bf16x8*>(
                        &h[mt * 16 + l16][((ks + 1) * 32 + quad * 8) ^ sx]);
            }
            #pragma unroll
            for (int mt = 0; mt < 4; ++mt) {
                acc[mt][0] = __builtin_amdgcn_mfma_f32_16x16x32_bf16(b0buf[ks % 3], ac[mt], acc[mt][0], 0, 0, 0);
                acc[mt][1] = __builtin_amdgcn_mfma_f32_16x16x32_bf16(b1buf[ks % 3], ac[mt], acc[mt][1], 0, 0, 0);
            }
            #pragma unroll
            for (int mt = 0; mt < 4; ++mt) ac[mt] = an[mt];
        }
        __syncthreads();  // all reads of h1 complete before overwrite

        #pragma unroll
        for (int nt = 0; nt < 2; ++nt) {
            int n0 = (wave * 2 + nt) * 16 + quad * 4;
            #pragma unroll
            for (int mt = 0; mt < 4; ++mt) {
                bf16x4 pk;
                #pragma unroll
                for (int r = 0; r < 4; ++r)
                    pk[r] = (bf16_t)(acc[mt][nt][r] > 0.0f ? acc[mt][nt][r] : 0.0f);
                int m = mt * 16 + l16;
                *reinterpret_cast<bf16x4*>(&h[m][n0 ^ sx]) = pk;
            }
        }
    }
    __syncthreads();

    // phase 3: out = h2 @ W3^T + b3, then loss. 8 jobs (4 mt x 2 ot) on waves 0..7.
    if (wave < 8) {
        const int mt = wave >> 1;
        const int ot = wave & 1;
        const int o0 = ot * 16 + quad * 4;
        const long grow = row0 + mt * 16 + l16;

        // hoist gt/b3 loads above the K-loop (hide latency under MFMAs)
        float g[4], b3v[4];
        #pragma unroll
        for (int r = 0; r < 4; ++r) {
            bool v = (o0 + r) < OUT_DIM;
            g[r]   = v ? gt[grow * OUT_DIM + o0 + r] : -10000.0f;
            b3v[r] = v ? b3[o0 + r] : 0.0f;
        }

        f32x4 acc3a = {b3v[0], b3v[1], b3v[2], b3v[3]};  // bias via C-in
        f32x4 acc3b = {0.0f, 0.0f, 0.0f, 0.0f};
        const int rr = mt * 16 + l16;
        #pragma unroll
        for (int ks = 0; ks < 16; ks += 2) {
            bf16x8 bh0 = *reinterpret_cast<const bf16x8*>(&h[rr][(ks * 32 + quad * 8) ^ sx]);
            bf16x8 bh1 = *reinterpret_cast<const bf16x8*>(&h[rr][((ks + 1) * 32 + quad * 8) ^ sx]);
            bf16x8 aw0 = *reinterpret_cast<const bf16x8*>(W3f + (ks * 2 + ot) * 512 + lane * 8);
            bf16x8 aw1 = *reinterpret_cast<const bf16x8*>(W3f + ((ks + 1) * 2 + ot) * 512 + lane * 8);
            acc3a = __builtin_amdgcn_mfma_f32_16x16x32_bf16(aw0, bh0, acc3a, 0, 0, 0);
            acc3b = __builtin_amdgcn_mfma_f32_16x16x32_bf16(aw1, bh1, acc3b, 0, 0, 0);
        }

        float num = 0.0f, den = 0.0f;
        #pragma unroll
        for (int r = 0; r < 4; ++r) {
            if ((o0 + r) < OUT_DIM) {
                float pred = acc3a[r] + acc3b[r];
                if (g[r] > -5000.0f) {
                    float w = (floorf(pred * 2.0f) == floorf(g[r] * 2.0f)) ? 0.5f : 1.0f;
                    num += fabsf(pred * w - g[r] * w);
                    den += 1.0f;
                }
            }
        }
        #pragma unroll
        for (int off = 32; off > 0; off >>= 1) {
            num += __shfl_down(num, off);
            den += __shfl_down(den, off);
        }
        if (lane == 0) { redbuf[wave * 2] = num; redbuf[wave * 2 + 1] = den; }
    }
    __syncthreads();
    if (tid == 0) {
        float nB = 0.0f, dB = 0.0f;
        #pragma unroll
        for (int w = 0; w < 8; ++w) { nB += redbuf[w * 2]; dB += redbuf[w * 2 + 1]; }
        atomicAdd(accum, nB);
        atomicAdd(accum + 1, dB);
        __threadfence();
        unsigned prev = atomicAdd((unsigned*)(accum + 2), 1u);
        if (prev == gridDim.x - 1) {   // last block finalizes (no extra launch)
            __threadfence();
            float num = __hip_atomic_load(accum,     __ATOMIC_RELAXED, __HIP_MEMORY_SCOPE_AGENT);
            float den = __hip_atomic_load(accum + 1, __ATOMIC_RELAXED, __HIP_MEMORY_SCOPE_AGENT);
            out[0] = num / den;
        }
    }
}

extern "C" void kernel_launch(void* const* d_in, const int* in_sizes, int n_in,
                              void* d_out, int out_size, void* d_ws, size_t ws_size,
                              hipStream_t stream) {
    const float* V  = (const float*)d_in[0];
    const float* gt = (const float*)d_in[1];
    const float* W1 = (const float*)d_in[2];
    const float* b1 = (const float*)d_in[3];
    const float* W2 = (const float*)d_in[4];
    const float* b2 = (const float*)d_in[5];
    const float* W3 = (const float*)d_in[6];
    const float* b3 = (const float*)d_in[7];
    float* out = (float*)d_out;

    char* ws = (char*)d_ws;
    float* accum = (float*)ws;                                       // 2 floats + 1 ticket
    bf16_t* W2f = (bf16_t*)(ws + 16);                                // 512 KB
    bf16_t* W1f = (bf16_t*)(ws + 16 + 512 * 512 * 2);                // 32 KB
    bf16_t* W3f = (bf16_t*)(ws + 16 + 512 * 512 * 2 + 32 * 512 * 2); // 32 KB

    int Brows = in_sizes[0] / IN_DIM;   // 131072
    int grid = Brows / M_TILE;          // 2048

    prep_kernel<<<576, 512, 0, stream>>>(W1, W2, W3, W1f, W2f, W3f, accum);
    fused_kernel<<<grid, THREADS, 0, stream>>>(V, gt, b1, b2, b3, W1f, W2f, W3f, accum, out);
}